// Round 11
// baseline (537.980 us; speedup 1.0000x reference)
//
#include <hip/hip_runtime.h>
#include <hip/hip_bf16.h>

#define NN 100000
#define NE 1000000
#define NTILES 98   // ceil(NN/1024)

// f32 -> bf16 bits, round-to-nearest-even
__device__ __forceinline__ unsigned short f32_to_bf16_bits(float f){
  unsigned u = __float_as_uint(f);
  u += 0x7FFFu + ((u >> 16) & 1u);
  return (unsigned short)(u >> 16);
}
__device__ __forceinline__ float bf16_bits_to_f32(unsigned short u){
  return __uint_as_float((unsigned)u << 16);
}

// ============ edge_index dtype probe (int32 vs int64 storage) ============
__global__ void probe_i_k(const unsigned long long* __restrict__ ei, int* __restrict__ mode64){
  __shared__ int big;
  if(threadIdx.x==0) big=0;
  __syncthreads();
  int t = threadIdx.x;
  for(int i=0;i<16;i++){
    long idx = (long)(t*16+i) * (NE/4096);
    if(ei[idx] >> 32) big = 1;
  }
  __syncthreads();
  if(t==0) *mode64 = big ? 0 : 1;
}

__device__ __forceinline__ int load_idx(const void* ei, long e, int m64){
  return m64 ? (int)((const long long*)ei)[e] : ((const int*)ei)[e];
}

// ================= CSR build (single-phase scatter) =================
// R8 lesson: 1M random-line scatter has ~64MB writeback floor (~73us);
// two-phase binning loses (concurrent blocks defeat bucket L2 blocking).

__global__ void zero_i32_k(int* __restrict__ p, int n){
  int i = blockIdx.x*256 + threadIdx.x;
  if(i<n) p[i]=0;
}

__global__ void hist_k(const void* __restrict__ ei, const int* __restrict__ mode,
                       int* __restrict__ deg){
  int e = blockIdx.x*256 + threadIdx.x;
  int m64 = *mode;
  if(e<NE) atomicAdd(&deg[load_idx(ei, e, m64)], 1);
}

__global__ void scan_tiles_k(const int* __restrict__ deg, int* __restrict__ partial,
                             int* __restrict__ tileSums){
  __shared__ int lds[256];
  int t = threadIdx.x;
  int base = blockIdx.x*1024 + t*4;
  int v0 = (base+0<NN)?deg[base+0]:0;
  int v1 = (base+1<NN)?deg[base+1]:0;
  int v2 = (base+2<NN)?deg[base+2]:0;
  int v3 = (base+3<NN)?deg[base+3]:0;
  int s = v0+v1+v2+v3;
  lds[t]=s; __syncthreads();
  for(int off=1; off<256; off<<=1){
    int x = (t>=off)? lds[t-off]:0;
    __syncthreads();
    lds[t]+=x;
    __syncthreads();
  }
  int excl = lds[t]-s;
  if(t==255) tileSums[blockIdx.x]=lds[255];
  if(base+0<NN) partial[base+0]=excl;
  if(base+1<NN) partial[base+1]=excl+v0;
  if(base+2<NN) partial[base+2]=excl+v0+v1;
  if(base+3<NN) partial[base+3]=excl+v0+v1+v2;
}

__global__ void scan_top_k(const int* __restrict__ tileSums, int* __restrict__ tileOff){
  if(threadIdx.x==0){
    int acc=0;
    for(int b=0;b<NTILES;b++){ tileOff[b]=acc; acc+=tileSums[b]; }
  }
}

__global__ void scan_add_k(const int* __restrict__ partial, const int* __restrict__ tileOff,
                           int* __restrict__ offsets, int* __restrict__ cursor){
  int i = blockIdx.x*256+threadIdx.x;
  if(i<NN){ int o = partial[i]+tileOff[i>>10]; offsets[i]=o; cursor[i]=o; }
  if(i==0) offsets[NN]=NE;
}

// packed CSR payload: .x = col, .y = edge weight bits
__global__ void fill_k(const void* __restrict__ ei, const int* __restrict__ mode,
                       const float* __restrict__ ew, int* __restrict__ cursor,
                       int2* __restrict__ csr_cw){
  int e = blockIdx.x*256+threadIdx.x;
  int m64 = *mode;
  if(e<NE){
    int r = load_idx(ei, e,          m64);
    int c = load_idx(ei, (long)NE+e, m64);
    int slot = atomicAdd(&cursor[r],1);
    csr_cw[slot] = make_int2(c, __float_as_int(ew[e]));
  }
}

// ============ input projection: h = x @ Wp^T + bp ============

__global__ void proj_k(const float* __restrict__ x, const float* __restrict__ Wp,
                       const float* __restrict__ bp, float* __restrict__ h){
  int tid = blockIdx.x*256+threadIdx.x;
  int n = tid>>6, j = tid&63;
  if(n>=NN) return;
  float acc = bp[j];
  #pragma unroll
  for(int k=0;k<8;k++) acc += x[n*8+k]*Wp[j*8+k];
  h[(long)n*64+j]=acc;
}

// ========== dual GEMM: hs = h@Ws^T+bs, hn = h@Wn^T+bn — both bf16 out ==========
// R10 retile: 128 nodes x 64 cols per block, 8x4 acc per thread -> 16 b128
// LDS reads feed 256 FMAs per k4 (was 12:128). Node map n=m*16+ty keeps the
// 8 sh reads on distinct banks. R5 lesson: unroll 2 + bounded occupancy to
// avoid VGPR=256 spill. LDS 67.5KB -> 2 blocks/CU -> launch_bounds(256,2).

__global__ __launch_bounds__(256, 2) void gemm_k(const float* __restrict__ h,
    const float* __restrict__ Ws, const float* __restrict__ bs,
    const float* __restrict__ Wn, const float* __restrict__ bn,
    unsigned short* __restrict__ hsb, unsigned short* __restrict__ hnb){
  __shared__ float sh[128][68];
  __shared__ float sws[64*64];
  __shared__ float swn[64*64];
  int tid = threadIdx.x;
  int n0 = blockIdx.x*128;
  {
    // h staging: 128 rows, 2 threads/row, 8 float4 each
    int r = tid>>1, halfc = (tid&1)*32;
    #pragma unroll
    for(int i=0;i<8;i++){
      int col = halfc + i*4;
      float4 hv = make_float4(0.f,0.f,0.f,0.f);
      if(n0+r<NN) hv = *(const float4*)(h + (long)(n0+r)*64 + col);
      *(float4*)&sh[r][col] = hv;
    }
    // W staging: 64 rows, 4 threads/row, 4 float4 each, XOR-swizzled
    int wr = tid>>2, q = tid&3;
    int off = 4*((wr>>2)&7);
    #pragma unroll
    for(int i=0;i<4;i++){
      int col = q*16 + i*4;
      int scol = col ^ off;
      *(float4*)&sws[wr*64+scol] = *(const float4*)(Ws + wr*64 + col);
      *(float4*)&swn[wr*64+scol] = *(const float4*)(Wn + wr*64 + col);
    }
  }
  __syncthreads();
  int tx = tid&15, ty = tid>>4;   // ty 0..15
  float accs[8][4]={{0.f}}, accn[8][4]={{0.f}};
  int woff = 4*(tx&7);
  #pragma unroll 2
  for(int k=0;k<64;k+=4){
    float4 hv[8];
    #pragma unroll
    for(int m=0;m<8;m++) hv[m] = *(float4*)&sh[m*16+ty][k];
    int sk = k ^ woff;
    #pragma unroll
    for(int c=0;c<4;c++){
      float4 w1 = *(float4*)&sws[(tx*4+c)*64 + sk];
      float4 w2 = *(float4*)&swn[(tx*4+c)*64 + sk];
      #pragma unroll
      for(int m=0;m<8;m++){
        accs[m][c] += hv[m].x*w1.x + hv[m].y*w1.y + hv[m].z*w1.z + hv[m].w*w1.w;
        accn[m][c] += hv[m].x*w2.x + hv[m].y*w2.y + hv[m].z*w2.z + hv[m].w*w2.w;
      }
    }
  }
  float4 bsv = *(const float4*)(bs + tx*4);
  float4 bnv = *(const float4*)(bn + tx*4);
  const float* bsp = (const float*)&bsv;
  const float* bnp = (const float*)&bnv;
  #pragma unroll
  for(int m=0;m<8;m++){
    int n = n0 + m*16 + ty;
    if(n>=NN) continue;
    ushort4 o1, o2;
    unsigned short* p1=(unsigned short*)&o1;
    unsigned short* p2=(unsigned short*)&o2;
    #pragma unroll
    for(int c=0;c<4;c++){
      p1[c] = f32_to_bf16_bits(accs[m][c]+bsp[c]);
      p2[c] = f32_to_bf16_bits(accn[m][c]+bnp[c]);
    }
    *(ushort4*)(hsb + (long)n*64 + tx*4) = o1;
    *(ushort4*)(hnb + (long)n*64 + tx*4) = o2;
  }
}

// ========== fused aggregate + LN + leaky + residual ==========
// R6: coalesced int2 metadata + __shfl broadcast. R10: 8-deep gather
// pipeline (deg~10 -> one MLP round), hs read as bf16.

__global__ __launch_bounds__(256) void agg_k(
    const float* __restrict__ h, const unsigned short* __restrict__ hsb,
    const unsigned short* __restrict__ hb,
    const int* __restrict__ offsets, const int2* __restrict__ csr_cw,
    const float* __restrict__ Wedge, const float* __restrict__ gamma, const float* __restrict__ beta,
    float* __restrict__ h_out){
  int wid = (blockIdx.x*256 + threadIdx.x) >> 6;
  int lane = threadIdx.x & 63;
  if(wid >= NN) return;
  int n = wid;
  float we = Wedge[lane];
  float hres = h[(long)n*64+lane];
  int s = __builtin_amdgcn_readfirstlane(offsets[n]);
  int e = __builtin_amdgcn_readfirstlane(offsets[n+1]);
  float acc = 0.f;
  for(int base = s; base < e; base += 64){
    int m = e - base; if(m > 64) m = 64;
    int2 cw = make_int2(0, 0);
    if(lane < m) cw = csr_cw[base + lane];
    int   myc = cw.x;
    float myw = __int_as_float(cw.y);
    int j = 0;
    for(; j + 8 <= m; j += 8){
      int c0=__shfl(myc,j+0,64); float w0=__shfl(myw,j+0,64);
      int c1=__shfl(myc,j+1,64); float w1=__shfl(myw,j+1,64);
      int c2=__shfl(myc,j+2,64); float w2=__shfl(myw,j+2,64);
      int c3=__shfl(myc,j+3,64); float w3=__shfl(myw,j+3,64);
      int c4=__shfl(myc,j+4,64); float w4=__shfl(myw,j+4,64);
      int c5=__shfl(myc,j+5,64); float w5=__shfl(myw,j+5,64);
      int c6=__shfl(myc,j+6,64); float w6=__shfl(myw,j+6,64);
      int c7=__shfl(myc,j+7,64); float w7=__shfl(myw,j+7,64);
      unsigned short u0=hb[(long)c0*64+lane], u1=hb[(long)c1*64+lane];
      unsigned short u2=hb[(long)c2*64+lane], u3=hb[(long)c3*64+lane];
      unsigned short u4=hb[(long)c4*64+lane], u5=hb[(long)c5*64+lane];
      unsigned short u6=hb[(long)c6*64+lane], u7=hb[(long)c7*64+lane];
      acc += bf16_bits_to_f32(u0)/(1.0f+__expf(-w0*we));
      acc += bf16_bits_to_f32(u1)/(1.0f+__expf(-w1*we));
      acc += bf16_bits_to_f32(u2)/(1.0f+__expf(-w2*we));
      acc += bf16_bits_to_f32(u3)/(1.0f+__expf(-w3*we));
      acc += bf16_bits_to_f32(u4)/(1.0f+__expf(-w4*we));
      acc += bf16_bits_to_f32(u5)/(1.0f+__expf(-w5*we));
      acc += bf16_bits_to_f32(u6)/(1.0f+__expf(-w6*we));
      acc += bf16_bits_to_f32(u7)/(1.0f+__expf(-w7*we));
    }
    for(; j + 4 <= m; j += 4){
      int c0=__shfl(myc,j+0,64); float w0=__shfl(myw,j+0,64);
      int c1=__shfl(myc,j+1,64); float w1=__shfl(myw,j+1,64);
      int c2=__shfl(myc,j+2,64); float w2=__shfl(myw,j+2,64);
      int c3=__shfl(myc,j+3,64); float w3=__shfl(myw,j+3,64);
      unsigned short u0=hb[(long)c0*64+lane], u1=hb[(long)c1*64+lane];
      unsigned short u2=hb[(long)c2*64+lane], u3=hb[(long)c3*64+lane];
      acc += bf16_bits_to_f32(u0)/(1.0f+__expf(-w0*we));
      acc += bf16_bits_to_f32(u1)/(1.0f+__expf(-w1*we));
      acc += bf16_bits_to_f32(u2)/(1.0f+__expf(-w2*we));
      acc += bf16_bits_to_f32(u3)/(1.0f+__expf(-w3*we));
    }
    for(; j < m; ++j){
      int   c  = __shfl(myc, j, 64);
      float wv = __shfl(myw, j, 64);
      acc += bf16_bits_to_f32(hb[(long)c*64+lane])/(1.0f+__expf(-wv*we));
    }
  }
  float v = bf16_bits_to_f32(hsb[(long)n*64+lane]) + acc;
  float sum = v, sumsq = v*v;
  #pragma unroll
  for(int off=32; off; off>>=1){
    sum   += __shfl_xor(sum,   off, 64);
    sumsq += __shfl_xor(sumsq, off, 64);
  }
  float mu  = sum * (1.f/64.f);
  float var = sumsq * (1.f/64.f) - mu*mu;
  float o = (v - mu) * rsqrtf(var + 1e-5f) * gamma[lane] + beta[lane];
  o = (o >= 0.f) ? o : 0.2f*o;
  h_out[(long)n*64+lane] = hres + o;
}

// ================= host launch =================

static inline char* align256(char* p){
  return (char*)(((uintptr_t)p + 255) & ~(uintptr_t)255);
}

extern "C" void kernel_launch(void* const* d_in, const int* in_sizes, int n_in,
                              void* d_out, int out_size, void* d_ws, size_t ws_size,
                              hipStream_t stream) {
  const float* x      = (const float*)d_in[0];
  const void*  ei     = d_in[1];                 // [2, NE], int32 (probed vs int64)
  const float* ew     = (const float*)d_in[2];
  const float* Wp     = (const float*)d_in[3];
  const float* bp     = (const float*)d_in[4];
  const float* Wself  = (const float*)d_in[5];
  const float* bself  = (const float*)d_in[6];
  const float* Wneigh = (const float*)d_in[7];
  const float* bneigh = (const float*)d_in[8];
  const float* Wedge  = (const float*)d_in[9];
  const float* gamma  = (const float*)d_in[10];
  const float* beta   = (const float*)d_in[11];
  float* out          = (float*)d_out;           // fp32 output (reference dtype)

  char* w = (char*)d_ws;
  float* h        = (float*)w;  w = align256(w + (size_t)NN*64*4);
  unsigned short* hsb = (unsigned short*)w;  w = align256(w + (size_t)NN*64*2);
  unsigned short* hnb = (unsigned short*)w;  w = align256(w + (size_t)NN*64*2);
  int*   deg      = (int*)w;    w = align256(w + (size_t)NN*4);
  int*   partial  = (int*)w;    w = align256(w + (size_t)NN*4);
  int*   tileSum  = (int*)w;    w = align256(w + (size_t)NTILES*4);
  int*   tileOff  = (int*)w;    w = align256(w + (size_t)NTILES*4);
  int*   offsets  = (int*)w;    w = align256(w + (size_t)(NN+1)*4);
  int*   cursor   = (int*)w;    w = align256(w + (size_t)NN*4);
  int*   mode64   = (int*)w;    w = align256(w + 4);
  int2*  csr_cw   = (int2*)w;   w = align256(w + (size_t)NE*8);

  probe_i_k<<<1, 256, 0, stream>>>((const unsigned long long*)ei, mode64);

  zero_i32_k<<<(NN+255)/256, 256, 0, stream>>>(deg, NN);
  hist_k<<<(NE+255)/256, 256, 0, stream>>>(ei, mode64, deg);
  scan_tiles_k<<<NTILES, 256, 0, stream>>>(deg, partial, tileSum);
  scan_top_k<<<1, 64, 0, stream>>>(tileSum, tileOff);
  scan_add_k<<<(NN+255)/256, 256, 0, stream>>>(partial, tileOff, offsets, cursor);
  fill_k<<<(NE+255)/256, 256, 0, stream>>>(ei, mode64, ew, cursor, csr_cw);

  proj_k<<<(NN*64+255)/256, 256, 0, stream>>>(x, Wp, bp, h);

  const int gemmBlocks = (NN + 127)/128;
  const int aggBlocks  = (NN*64 + 255)/256;
  for(int l=0; l<3; ++l){
    gemm_k<<<gemmBlocks, 256, 0, stream>>>(h, Wself + (size_t)l*64*64, bself + l*64,
                                           Wneigh + (size_t)l*64*64, bneigh + l*64, hsb, hnb);
    float* dst = (l < 2) ? h : out;
    agg_k<<<aggBlocks, 256, 0, stream>>>(h, hsb, hnb, offsets, csr_cw,
                                         Wedge + l*64, gamma + l*64, beta + l*64, dst);
  }
}

// Round 12
// 498.970 us; speedup vs baseline: 1.0782x; 1.0782x over previous
//
#include <hip/hip_runtime.h>
#include <hip/hip_bf16.h>

#define NN 100000
#define NE 1000000
#define NTILES 98   // ceil(NN/1024)

// f32 -> bf16 bits, round-to-nearest-even
__device__ __forceinline__ unsigned short f32_to_bf16_bits(float f){
  unsigned u = __float_as_uint(f);
  u += 0x7FFFu + ((u >> 16) & 1u);
  return (unsigned short)(u >> 16);
}
__device__ __forceinline__ float bf16_bits_to_f32(unsigned short u){
  return __uint_as_float((unsigned)u << 16);
}

// ============ edge_index dtype probe (int32 vs int64 storage) ============
__global__ void probe_i_k(const unsigned long long* __restrict__ ei, int* __restrict__ mode64){
  __shared__ int big;
  if(threadIdx.x==0) big=0;
  __syncthreads();
  int t = threadIdx.x;
  for(int i=0;i<16;i++){
    long idx = (long)(t*16+i) * (NE/4096);
    if(ei[idx] >> 32) big = 1;
  }
  __syncthreads();
  if(t==0) *mode64 = big ? 0 : 1;
}

__device__ __forceinline__ int load_idx(const void* ei, long e, int m64){
  return m64 ? (int)((const long long*)ei)[e] : ((const int*)ei)[e];
}

// ================= CSR build (single-phase scatter) =================
// R8 lesson: 1M random-line scatter has ~64MB writeback floor (~73us at
// nominal clock); binning loses. fill_k serves as in-run clock reference.

__global__ void zero_i32_k(int* __restrict__ p, int n){
  int i = blockIdx.x*256 + threadIdx.x;
  if(i<n) p[i]=0;
}

__global__ void hist_k(const void* __restrict__ ei, const int* __restrict__ mode,
                       int* __restrict__ deg){
  int e = blockIdx.x*256 + threadIdx.x;
  int m64 = *mode;
  if(e<NE) atomicAdd(&deg[load_idx(ei, e, m64)], 1);
}

__global__ void scan_tiles_k(const int* __restrict__ deg, int* __restrict__ partial,
                             int* __restrict__ tileSums){
  __shared__ int lds[256];
  int t = threadIdx.x;
  int base = blockIdx.x*1024 + t*4;
  int v0 = (base+0<NN)?deg[base+0]:0;
  int v1 = (base+1<NN)?deg[base+1]:0;
  int v2 = (base+2<NN)?deg[base+2]:0;
  int v3 = (base+3<NN)?deg[base+3]:0;
  int s = v0+v1+v2+v3;
  lds[t]=s; __syncthreads();
  for(int off=1; off<256; off<<=1){
    int x = (t>=off)? lds[t-off]:0;
    __syncthreads();
    lds[t]+=x;
    __syncthreads();
  }
  int excl = lds[t]-s;
  if(t==255) tileSums[blockIdx.x]=lds[255];
  if(base+0<NN) partial[base+0]=excl;
  if(base+1<NN) partial[base+1]=excl+v0;
  if(base+2<NN) partial[base+2]=excl+v0+v1;
  if(base+3<NN) partial[base+3]=excl+v0+v1+v2;
}

__global__ void scan_top_k(const int* __restrict__ tileSums, int* __restrict__ tileOff){
  if(threadIdx.x==0){
    int acc=0;
    for(int b=0;b<NTILES;b++){ tileOff[b]=acc; acc+=tileSums[b]; }
  }
}

__global__ void scan_add_k(const int* __restrict__ partial, const int* __restrict__ tileOff,
                           int* __restrict__ offsets, int* __restrict__ cursor){
  int i = blockIdx.x*256+threadIdx.x;
  if(i<NN){ int o = partial[i]+tileOff[i>>10]; offsets[i]=o; cursor[i]=o; }
  if(i==0) offsets[NN]=NE;
}

// packed CSR payload: .x = col, .y = edge weight bits
__global__ void fill_k(const void* __restrict__ ei, const int* __restrict__ mode,
                       const float* __restrict__ ew, int* __restrict__ cursor,
                       int2* __restrict__ csr_cw){
  int e = blockIdx.x*256+threadIdx.x;
  int m64 = *mode;
  if(e<NE){
    int r = load_idx(ei, e,          m64);
    int c = load_idx(ei, (long)NE+e, m64);
    int slot = atomicAdd(&cursor[r],1);
    csr_cw[slot] = make_int2(c, __float_as_int(ew[e]));
  }
}

// ============ input projection: h = x @ Wp^T + bp ============

__global__ void proj_k(const float* __restrict__ x, const float* __restrict__ Wp,
                       const float* __restrict__ bp, float* __restrict__ h){
  int tid = blockIdx.x*256+threadIdx.x;
  int n = tid>>6, j = tid&63;
  if(n>=NN) return;
  float acc = bp[j];
  #pragma unroll
  for(int k=0;k<8;k++) acc += x[n*8+k]*Wp[j*8+k];
  h[(long)n*64+j]=acc;
}

// ========== dual GEMM (64-tile, R9-proven): hs,hn -> bf16 ==========
// R11 lesson: 128-tile retile (2 blocks/CU) + slow-clock run measured worse;
// revert to the 64-tile shape that benched 495us. R5 lesson: unroll 2 +
// launch_bounds(256,3). hs/hn both stored bf16 (pure traffic reduction).

__global__ __launch_bounds__(256, 3) void gemm_k(const float* __restrict__ h,
    const float* __restrict__ Ws, const float* __restrict__ bs,
    const float* __restrict__ Wn, const float* __restrict__ bn,
    unsigned short* __restrict__ hsb, unsigned short* __restrict__ hnb){
  __shared__ float sh[64][68];
  __shared__ float sws[64*64];
  __shared__ float swn[64*64];
  int tid = threadIdx.x;
  int n0 = blockIdx.x*64;
  {
    int r = tid>>2, q = tid&3;
    int off = 4*((r>>2)&7);
    #pragma unroll
    for(int i=0;i<4;i++){
      int col = q*16 + i*4;
      float4 hv = make_float4(0.f,0.f,0.f,0.f);
      if(n0+r<NN) hv = *(const float4*)(h + (long)(n0+r)*64 + col);
      *(float4*)&sh[r][col] = hv;
      int scol = col ^ off;
      *(float4*)&sws[r*64+scol] = *(const float4*)(Ws + r*64 + col);
      *(float4*)&swn[r*64+scol] = *(const float4*)(Wn + r*64 + col);
    }
  }
  __syncthreads();
  int ty = tid>>4, tx = tid&15;
  float accs[4][4]={{0.f}}, accn[4][4]={{0.f}};
  int woff = 4*(tx&7);
  #pragma unroll 2
  for(int k=0;k<64;k+=4){
    float4 hv[4];
    #pragma unroll
    for(int m=0;m<4;m++) hv[m] = *(float4*)&sh[ty*4+m][k];
    int sk = k ^ woff;
    #pragma unroll
    for(int c=0;c<4;c++){
      float4 w1 = *(float4*)&sws[(tx*4+c)*64 + sk];
      float4 w2 = *(float4*)&swn[(tx*4+c)*64 + sk];
      #pragma unroll
      for(int m=0;m<4;m++){
        accs[m][c] += hv[m].x*w1.x + hv[m].y*w1.y + hv[m].z*w1.z + hv[m].w*w1.w;
        accn[m][c] += hv[m].x*w2.x + hv[m].y*w2.y + hv[m].z*w2.z + hv[m].w*w2.w;
      }
    }
  }
  float4 bsv = *(const float4*)(bs + tx*4);
  float4 bnv = *(const float4*)(bn + tx*4);
  const float* bsp = (const float*)&bsv;
  const float* bnp = (const float*)&bnv;
  #pragma unroll
  for(int m=0;m<4;m++){
    int n = n0 + ty*4 + m;
    if(n>=NN) continue;
    ushort4 o1, o2;
    unsigned short* p1=(unsigned short*)&o1;
    unsigned short* p2=(unsigned short*)&o2;
    #pragma unroll
    for(int c=0;c<4;c++){
      p1[c] = f32_to_bf16_bits(accs[m][c]+bsp[c]);
      p2[c] = f32_to_bf16_bits(accn[m][c]+bnp[c]);
    }
    *(ushort4*)(hsb + (long)n*64 + tx*4) = o1;
    *(ushort4*)(hnb + (long)n*64 + tx*4) = o2;
  }
}

// ========== fused aggregate + LN + leaky + residual ==========
// R6: coalesced int2 metadata + __shfl broadcast; 4-deep gather pipeline
// (R10-proven). hs and hn both read as bf16 bits, fp32 accumulate.

__global__ __launch_bounds__(256) void agg_k(
    const float* __restrict__ h, const unsigned short* __restrict__ hsb,
    const unsigned short* __restrict__ hb,
    const int* __restrict__ offsets, const int2* __restrict__ csr_cw,
    const float* __restrict__ Wedge, const float* __restrict__ gamma, const float* __restrict__ beta,
    float* __restrict__ h_out){
  int wid = (blockIdx.x*256 + threadIdx.x) >> 6;
  int lane = threadIdx.x & 63;
  if(wid >= NN) return;
  int n = wid;
  float we = Wedge[lane];
  float hres = h[(long)n*64+lane];
  int s = __builtin_amdgcn_readfirstlane(offsets[n]);
  int e = __builtin_amdgcn_readfirstlane(offsets[n+1]);
  float acc = 0.f;
  for(int base = s; base < e; base += 64){
    int m = e - base; if(m > 64) m = 64;
    int2 cw = make_int2(0, 0);
    if(lane < m) cw = csr_cw[base + lane];
    int   myc = cw.x;
    float myw = __int_as_float(cw.y);
    int j = 0;
    for(; j + 4 <= m; j += 4){
      int c0=__shfl(myc,j+0,64); float w0=__shfl(myw,j+0,64);
      int c1=__shfl(myc,j+1,64); float w1=__shfl(myw,j+1,64);
      int c2=__shfl(myc,j+2,64); float w2=__shfl(myw,j+2,64);
      int c3=__shfl(myc,j+3,64); float w3=__shfl(myw,j+3,64);
      unsigned short u0=hb[(long)c0*64+lane], u1=hb[(long)c1*64+lane];
      unsigned short u2=hb[(long)c2*64+lane], u3=hb[(long)c3*64+lane];
      acc += bf16_bits_to_f32(u0)/(1.0f+__expf(-w0*we));
      acc += bf16_bits_to_f32(u1)/(1.0f+__expf(-w1*we));
      acc += bf16_bits_to_f32(u2)/(1.0f+__expf(-w2*we));
      acc += bf16_bits_to_f32(u3)/(1.0f+__expf(-w3*we));
    }
    for(; j < m; ++j){
      int   c  = __shfl(myc, j, 64);
      float wv = __shfl(myw, j, 64);
      acc += bf16_bits_to_f32(hb[(long)c*64+lane])/(1.0f+__expf(-wv*we));
    }
  }
  float v = bf16_bits_to_f32(hsb[(long)n*64+lane]) + acc;
  float sum = v, sumsq = v*v;
  #pragma unroll
  for(int off=32; off; off>>=1){
    sum   += __shfl_xor(sum,   off, 64);
    sumsq += __shfl_xor(sumsq, off, 64);
  }
  float mu  = sum * (1.f/64.f);
  float var = sumsq * (1.f/64.f) - mu*mu;
  float o = (v - mu) * rsqrtf(var + 1e-5f) * gamma[lane] + beta[lane];
  o = (o >= 0.f) ? o : 0.2f*o;
  h_out[(long)n*64+lane] = hres + o;
}

// ================= host launch =================

static inline char* align256(char* p){
  return (char*)(((uintptr_t)p + 255) & ~(uintptr_t)255);
}

extern "C" void kernel_launch(void* const* d_in, const int* in_sizes, int n_in,
                              void* d_out, int out_size, void* d_ws, size_t ws_size,
                              hipStream_t stream) {
  const float* x      = (const float*)d_in[0];
  const void*  ei     = d_in[1];                 // [2, NE], int32 (probed vs int64)
  const float* ew     = (const float*)d_in[2];
  const float* Wp     = (const float*)d_in[3];
  const float* bp     = (const float*)d_in[4];
  const float* Wself  = (const float*)d_in[5];
  const float* bself  = (const float*)d_in[6];
  const float* Wneigh = (const float*)d_in[7];
  const float* bneigh = (const float*)d_in[8];
  const float* Wedge  = (const float*)d_in[9];
  const float* gamma  = (const float*)d_in[10];
  const float* beta   = (const float*)d_in[11];
  float* out          = (float*)d_out;           // fp32 output (reference dtype)

  char* w = (char*)d_ws;
  float* h        = (float*)w;  w = align256(w + (size_t)NN*64*4);
  unsigned short* hsb = (unsigned short*)w;  w = align256(w + (size_t)NN*64*2);
  unsigned short* hnb = (unsigned short*)w;  w = align256(w + (size_t)NN*64*2);
  int*   deg      = (int*)w;    w = align256(w + (size_t)NN*4);
  int*   partial  = (int*)w;    w = align256(w + (size_t)NN*4);
  int*   tileSum  = (int*)w;    w = align256(w + (size_t)NTILES*4);
  int*   tileOff  = (int*)w;    w = align256(w + (size_t)NTILES*4);
  int*   offsets  = (int*)w;    w = align256(w + (size_t)(NN+1)*4);
  int*   cursor   = (int*)w;    w = align256(w + (size_t)NN*4);
  int*   mode64   = (int*)w;    w = align256(w + 4);
  int2*  csr_cw   = (int2*)w;   w = align256(w + (size_t)NE*8);

  probe_i_k<<<1, 256, 0, stream>>>((const unsigned long long*)ei, mode64);

  zero_i32_k<<<(NN+255)/256, 256, 0, stream>>>(deg, NN);
  hist_k<<<(NE+255)/256, 256, 0, stream>>>(ei, mode64, deg);
  scan_tiles_k<<<NTILES, 256, 0, stream>>>(deg, partial, tileSum);
  scan_top_k<<<1, 64, 0, stream>>>(tileSum, tileOff);
  scan_add_k<<<(NN+255)/256, 256, 0, stream>>>(partial, tileOff, offsets, cursor);
  fill_k<<<(NE+255)/256, 256, 0, stream>>>(ei, mode64, ew, cursor, csr_cw);

  proj_k<<<(NN*64+255)/256, 256, 0, stream>>>(x, Wp, bp, h);

  const int gemmBlocks = (NN + 63)/64;
  const int aggBlocks  = (NN*64 + 255)/256;
  for(int l=0; l<3; ++l){
    gemm_k<<<gemmBlocks, 256, 0, stream>>>(h, Wself + (size_t)l*64*64, bself + l*64,
                                           Wneigh + (size_t)l*64*64, bneigh + l*64, hsb, hnb);
    float* dst = (l < 2) ? h : out;
    agg_k<<<aggBlocks, 256, 0, stream>>>(h, hsb, hnb, offsets, csr_cw,
                                         Wedge + l*64, gamma + l*64, beta + l*64, dst);
  }
}

// Round 13
// 476.611 us; speedup vs baseline: 1.1288x; 1.0469x over previous
//
#include <hip/hip_runtime.h>
#include <hip/hip_bf16.h>

#define NN 100000
#define NE 1000000
#define NTILES 98   // ceil(NN/1024)

typedef short bf16x8 __attribute__((ext_vector_type(8)));
typedef float f32x4  __attribute__((ext_vector_type(4)));

// f32 -> bf16 bits, round-to-nearest-even
__device__ __forceinline__ unsigned short f32_to_bf16_bits(float f){
  unsigned u = __float_as_uint(f);
  u += 0x7FFFu + ((u >> 16) & 1u);
  return (unsigned short)(u >> 16);
}
__device__ __forceinline__ float bf16_bits_to_f32(unsigned short u){
  return __uint_as_float((unsigned)u << 16);
}

// ============ edge_index dtype probe (int32 vs int64 storage) ============
__global__ void probe_i_k(const unsigned long long* __restrict__ ei, int* __restrict__ mode64){
  __shared__ int big;
  if(threadIdx.x==0) big=0;
  __syncthreads();
  int t = threadIdx.x;
  for(int i=0;i<16;i++){
    long idx = (long)(t*16+i) * (NE/4096);
    if(ei[idx] >> 32) big = 1;
  }
  __syncthreads();
  if(t==0) *mode64 = big ? 0 : 1;
}

__device__ __forceinline__ int load_idx(const void* ei, long e, int m64){
  return m64 ? (int)((const long long*)ei)[e] : ((const int*)ei)[e];
}

// ================= CSR build (single-phase scatter) =================
// R8 lesson: 1M random-line scatter has ~64MB writeback floor (~73us at
// nominal clock); binning loses. fill_k serves as in-run clock reference.

__global__ void zero_i32_k(int* __restrict__ p, int n){
  int i = blockIdx.x*256 + threadIdx.x;
  if(i<n) p[i]=0;
}

__global__ void hist_k(const void* __restrict__ ei, const int* __restrict__ mode,
                       int* __restrict__ deg){
  int e = blockIdx.x*256 + threadIdx.x;
  int m64 = *mode;
  if(e<NE) atomicAdd(&deg[load_idx(ei, e, m64)], 1);
}

__global__ void scan_tiles_k(const int* __restrict__ deg, int* __restrict__ partial,
                             int* __restrict__ tileSums){
  __shared__ int lds[256];
  int t = threadIdx.x;
  int base = blockIdx.x*1024 + t*4;
  int v0 = (base+0<NN)?deg[base+0]:0;
  int v1 = (base+1<NN)?deg[base+1]:0;
  int v2 = (base+2<NN)?deg[base+2]:0;
  int v3 = (base+3<NN)?deg[base+3]:0;
  int s = v0+v1+v2+v3;
  lds[t]=s; __syncthreads();
  for(int off=1; off<256; off<<=1){
    int x = (t>=off)? lds[t-off]:0;
    __syncthreads();
    lds[t]+=x;
    __syncthreads();
  }
  int excl = lds[t]-s;
  if(t==255) tileSums[blockIdx.x]=lds[255];
  if(base+0<NN) partial[base+0]=excl;
  if(base+1<NN) partial[base+1]=excl+v0;
  if(base+2<NN) partial[base+2]=excl+v0+v1;
  if(base+3<NN) partial[base+3]=excl+v0+v1+v2;
}

__global__ void scan_top_k(const int* __restrict__ tileSums, int* __restrict__ tileOff){
  if(threadIdx.x==0){
    int acc=0;
    for(int b=0;b<NTILES;b++){ tileOff[b]=acc; acc+=tileSums[b]; }
  }
}

__global__ void scan_add_k(const int* __restrict__ partial, const int* __restrict__ tileOff,
                           int* __restrict__ offsets, int* __restrict__ cursor){
  int i = blockIdx.x*256+threadIdx.x;
  if(i<NN){ int o = partial[i]+tileOff[i>>10]; offsets[i]=o; cursor[i]=o; }
  if(i==0) offsets[NN]=NE;
}

// packed CSR payload: .x = col, .y = edge weight bits
__global__ void fill_k(const void* __restrict__ ei, const int* __restrict__ mode,
                       const float* __restrict__ ew, int* __restrict__ cursor,
                       int2* __restrict__ csr_cw){
  int e = blockIdx.x*256+threadIdx.x;
  int m64 = *mode;
  if(e<NE){
    int r = load_idx(ei, e,          m64);
    int c = load_idx(ei, (long)NE+e, m64);
    int slot = atomicAdd(&cursor[r],1);
    csr_cw[slot] = make_int2(c, __float_as_int(ew[e]));
  }
}

// ============ input projection: h = x @ Wp^T + bp ============

__global__ void proj_k(const float* __restrict__ x, const float* __restrict__ Wp,
                       const float* __restrict__ bp, float* __restrict__ h){
  int tid = blockIdx.x*256+threadIdx.x;
  int n = tid>>6, j = tid&63;
  if(n>=NN) return;
  float acc = bp[j];
  #pragma unroll
  for(int k=0;k<8;k++) acc += x[n*8+k]*Wp[j*8+k];
  h[(long)n*64+j]=acc;
}

// ============ weight bf16 conversion (once per launch) ============
__global__ void cvt_w_k(const float* __restrict__ Wself, const float* __restrict__ Wneigh,
                        unsigned short* __restrict__ Wsb, unsigned short* __restrict__ Wnb){
  int i = blockIdx.x*256 + threadIdx.x;
  if(i < 3*64*64){
    Wsb[i] = f32_to_bf16_bits(Wself[i]);
    Wnb[i] = f32_to_bf16_bits(Wneigh[i]);
  }
}

// ========== dual GEMM via MFMA (R13): hs,hn -> bf16 ==========
// mfma_f32_16x16x32_bf16: A[m=lane&15][k=quad*8+j] (8 contiguous k per lane ->
// direct dwordx4 loads from h rows, no LDS staging), B[k=quad*8+j][n=lane&15]
// = Wsb[col-row][k] (contiguous, L1-resident). D: row=quad*4+reg, col=lane&15,
// repacked through 8.7KB LDS into coalesced ushort4 stores.
// Block = 16 nodes, 4 waves = 4 col-stripes of 16; 4 MFMA/wave cover both GEMMs.

__global__ __launch_bounds__(256) void gemm_mfma_k(const float* __restrict__ h,
    const unsigned short* __restrict__ Wsb, const float* __restrict__ bs,
    const unsigned short* __restrict__ Wnb, const float* __restrict__ bn,
    unsigned short* __restrict__ hsb, unsigned short* __restrict__ hnb){
  __shared__ float sD[2][16][68];
  int tid  = threadIdx.x;
  int lane = tid & 63, wv = tid >> 6;
  int n0 = blockIdx.x * 16;            // NN=100000 = 6250*16, no bounds needed
  int m = lane & 15, quad = lane >> 4;
  int c0 = wv * 16;
  // --- A fragments: h[n0+m][quad*8 + j] fp32 -> bf16 in-register ---
  const float* arow = h + (long)(n0+m)*64 + quad*8;
  float4 a0lo = *(const float4*)(arow);
  float4 a0hi = *(const float4*)(arow + 4);
  float4 a1lo = *(const float4*)(arow + 32);
  float4 a1hi = *(const float4*)(arow + 36);
  bf16x8 A0, A1;
  A0[0]=(short)f32_to_bf16_bits(a0lo.x); A0[1]=(short)f32_to_bf16_bits(a0lo.y);
  A0[2]=(short)f32_to_bf16_bits(a0lo.z); A0[3]=(short)f32_to_bf16_bits(a0lo.w);
  A0[4]=(short)f32_to_bf16_bits(a0hi.x); A0[5]=(short)f32_to_bf16_bits(a0hi.y);
  A0[6]=(short)f32_to_bf16_bits(a0hi.z); A0[7]=(short)f32_to_bf16_bits(a0hi.w);
  A1[0]=(short)f32_to_bf16_bits(a1lo.x); A1[1]=(short)f32_to_bf16_bits(a1lo.y);
  A1[2]=(short)f32_to_bf16_bits(a1lo.z); A1[3]=(short)f32_to_bf16_bits(a1lo.w);
  A1[4]=(short)f32_to_bf16_bits(a1hi.x); A1[5]=(short)f32_to_bf16_bits(a1hi.y);
  A1[6]=(short)f32_to_bf16_bits(a1hi.z); A1[7]=(short)f32_to_bf16_bits(a1hi.w);
  // --- B fragments: weight row (c0+m), two K halves, both matrices ---
  int crow = c0 + m;
  bf16x8 Bs0 = *(const bf16x8*)(Wsb + (long)crow*64 + quad*8);
  bf16x8 Bs1 = *(const bf16x8*)(Wsb + (long)crow*64 + 32 + quad*8);
  bf16x8 Bn0 = *(const bf16x8*)(Wnb + (long)crow*64 + quad*8);
  bf16x8 Bn1 = *(const bf16x8*)(Wnb + (long)crow*64 + 32 + quad*8);
  f32x4 accs = {0.f,0.f,0.f,0.f}, accn = {0.f,0.f,0.f,0.f};
  accs = __builtin_amdgcn_mfma_f32_16x16x32_bf16(A0, Bs0, accs, 0,0,0);
  accs = __builtin_amdgcn_mfma_f32_16x16x32_bf16(A1, Bs1, accs, 0,0,0);
  accn = __builtin_amdgcn_mfma_f32_16x16x32_bf16(A0, Bn0, accn, 0,0,0);
  accn = __builtin_amdgcn_mfma_f32_16x16x32_bf16(A1, Bn1, accn, 0,0,0);
  // --- bias + park in LDS (D: row=quad*4+r, col=c0+m) ---
  float bsv = bs[c0 + m], bnv = bn[c0 + m];
  #pragma unroll
  for(int r=0;r<4;r++){
    sD[0][quad*4+r][c0+m] = accs[r] + bsv;
    sD[1][quad*4+r][c0+m] = accn[r] + bnv;
  }
  __syncthreads();
  // --- coalesced bf16 stores: 2048 shorts / 256 threads = 8 each ---
  int g   = tid >> 7;          // 0..1
  int rem = tid & 127;
  int row = rem >> 3;          // 0..15
  int cg  = rem & 7;           // 8 groups of 8 cols
  float4 lo = *(float4*)&sD[g][row][cg*8];
  float4 hi = *(float4*)&sD[g][row][cg*8+4];
  ushort4 s0, s1;
  s0.x=f32_to_bf16_bits(lo.x); s0.y=f32_to_bf16_bits(lo.y);
  s0.z=f32_to_bf16_bits(lo.z); s0.w=f32_to_bf16_bits(lo.w);
  s1.x=f32_to_bf16_bits(hi.x); s1.y=f32_to_bf16_bits(hi.y);
  s1.z=f32_to_bf16_bits(hi.z); s1.w=f32_to_bf16_bits(hi.w);
  unsigned short* dst = (g ? hnb : hsb) + (long)(n0+row)*64 + cg*8;
  *(ushort4*)dst = s0;
  *(ushort4*)(dst+4) = s1;
}

// ========== fused aggregate + LN + leaky + residual ==========
// R6: coalesced int2 metadata + __shfl broadcast; 4-deep gather pipeline.
// hs and hn read as bf16 bits, fp32 accumulate.

__global__ __launch_bounds__(256) void agg_k(
    const float* __restrict__ h, const unsigned short* __restrict__ hsb,
    const unsigned short* __restrict__ hb,
    const int* __restrict__ offsets, const int2* __restrict__ csr_cw,
    const float* __restrict__ Wedge, const float* __restrict__ gamma, const float* __restrict__ beta,
    float* __restrict__ h_out){
  int wid = (blockIdx.x*256 + threadIdx.x) >> 6;
  int lane = threadIdx.x & 63;
  if(wid >= NN) return;
  int n = wid;
  float we = Wedge[lane];
  float hres = h[(long)n*64+lane];
  int s = __builtin_amdgcn_readfirstlane(offsets[n]);
  int e = __builtin_amdgcn_readfirstlane(offsets[n+1]);
  float acc = 0.f;
  for(int base = s; base < e; base += 64){
    int m = e - base; if(m > 64) m = 64;
    int2 cw = make_int2(0, 0);
    if(lane < m) cw = csr_cw[base + lane];
    int   myc = cw.x;
    float myw = __int_as_float(cw.y);
    int j = 0;
    for(; j + 4 <= m; j += 4){
      int c0=__shfl(myc,j+0,64); float w0=__shfl(myw,j+0,64);
      int c1=__shfl(myc,j+1,64); float w1=__shfl(myw,j+1,64);
      int c2=__shfl(myc,j+2,64); float w2=__shfl(myw,j+2,64);
      int c3=__shfl(myc,j+3,64); float w3=__shfl(myw,j+3,64);
      unsigned short u0=hb[(long)c0*64+lane], u1=hb[(long)c1*64+lane];
      unsigned short u2=hb[(long)c2*64+lane], u3=hb[(long)c3*64+lane];
      acc += bf16_bits_to_f32(u0)/(1.0f+__expf(-w0*we));
      acc += bf16_bits_to_f32(u1)/(1.0f+__expf(-w1*we));
      acc += bf16_bits_to_f32(u2)/(1.0f+__expf(-w2*we));
      acc += bf16_bits_to_f32(u3)/(1.0f+__expf(-w3*we));
    }
    for(; j < m; ++j){
      int   c  = __shfl(myc, j, 64);
      float wv = __shfl(myw, j, 64);
      acc += bf16_bits_to_f32(hb[(long)c*64+lane])/(1.0f+__expf(-wv*we));
    }
  }
  float v = bf16_bits_to_f32(hsb[(long)n*64+lane]) + acc;
  float sum = v, sumsq = v*v;
  #pragma unroll
  for(int off=32; off; off>>=1){
    sum   += __shfl_xor(sum,   off, 64);
    sumsq += __shfl_xor(sumsq, off, 64);
  }
  float mu  = sum * (1.f/64.f);
  float var = sumsq * (1.f/64.f) - mu*mu;
  float o = (v - mu) * rsqrtf(var + 1e-5f) * gamma[lane] + beta[lane];
  o = (o >= 0.f) ? o : 0.2f*o;
  h_out[(long)n*64+lane] = hres + o;
}

// ================= host launch =================

static inline char* align256(char* p){
  return (char*)(((uintptr_t)p + 255) & ~(uintptr_t)255);
}

extern "C" void kernel_launch(void* const* d_in, const int* in_sizes, int n_in,
                              void* d_out, int out_size, void* d_ws, size_t ws_size,
                              hipStream_t stream) {
  const float* x      = (const float*)d_in[0];
  const void*  ei     = d_in[1];                 // [2, NE], int32 (probed vs int64)
  const float* ew     = (const float*)d_in[2];
  const float* Wp     = (const float*)d_in[3];
  const float* bp     = (const float*)d_in[4];
  const float* Wself  = (const float*)d_in[5];
  const float* bself  = (const float*)d_in[6];
  const float* Wneigh = (const float*)d_in[7];
  const float* bneigh = (const float*)d_in[8];
  const float* Wedge  = (const float*)d_in[9];
  const float* gamma  = (const float*)d_in[10];
  const float* beta   = (const float*)d_in[11];
  float* out          = (float*)d_out;           // fp32 output (reference dtype)

  char* w = (char*)d_ws;
  float* h        = (float*)w;  w = align256(w + (size_t)NN*64*4);
  unsigned short* hsb = (unsigned short*)w;  w = align256(w + (size_t)NN*64*2);
  unsigned short* hnb = (unsigned short*)w;  w = align256(w + (size_t)NN*64*2);
  int*   deg      = (int*)w;    w = align256(w + (size_t)NN*4);
  int*   partial  = (int*)w;    w = align256(w + (size_t)NN*4);
  int*   tileSum  = (int*)w;    w = align256(w + (size_t)NTILES*4);
  int*   tileOff  = (int*)w;    w = align256(w + (size_t)NTILES*4);
  int*   offsets  = (int*)w;    w = align256(w + (size_t)(NN+1)*4);
  int*   cursor   = (int*)w;    w = align256(w + (size_t)NN*4);
  int*   mode64   = (int*)w;    w = align256(w + 4);
  unsigned short* Wsb = (unsigned short*)w; w = align256(w + (size_t)3*64*64*2);
  unsigned short* Wnb = (unsigned short*)w; w = align256(w + (size_t)3*64*64*2);
  int2*  csr_cw   = (int2*)w;   w = align256(w + (size_t)NE*8);

  probe_i_k<<<1, 256, 0, stream>>>((const unsigned long long*)ei, mode64);

  zero_i32_k<<<(NN+255)/256, 256, 0, stream>>>(deg, NN);
  hist_k<<<(NE+255)/256, 256, 0, stream>>>(ei, mode64, deg);
  scan_tiles_k<<<NTILES, 256, 0, stream>>>(deg, partial, tileSum);
  scan_top_k<<<1, 64, 0, stream>>>(tileSum, tileOff);
  scan_add_k<<<(NN+255)/256, 256, 0, stream>>>(partial, tileOff, offsets, cursor);
  fill_k<<<(NE+255)/256, 256, 0, stream>>>(ei, mode64, ew, cursor, csr_cw);

  cvt_w_k<<<(3*64*64+255)/256, 256, 0, stream>>>(Wself, Wneigh, Wsb, Wnb);
  proj_k<<<(NN*64+255)/256, 256, 0, stream>>>(x, Wp, bp, h);

  const int gemmBlocks = NN/16;   // 6250
  const int aggBlocks  = (NN*64 + 255)/256;
  for(int l=0; l<3; ++l){
    gemm_mfma_k<<<gemmBlocks, 256, 0, stream>>>(h, Wsb + (size_t)l*64*64, bself + l*64,
                                                Wnb + (size_t)l*64*64, bneigh + l*64, hsb, hnb);
    float* dst = (l < 2) ? h : out;
    agg_k<<<aggBlocks, 256, 0, stream>>>(h, hsb, hnb, offsets, csr_cw,
                                         Wedge + l*64, gamma + l*64, beta + l*64, dst);
  }
}